// Round 11
// baseline (235.734 us; speedup 1.0000x reference)
//
#include <hip/hip_runtime.h>
#include <math.h>

// Problem: B=8, N=192, C=16.
// out[b,i,j,k] = argmax(t0[b,i,:]) * argmax(t1[b,j,:]) * argmax(t2[b,k,:])
//                * (i!=j && i!=k && j!=k),  written as int32.
// Output: 8*192^3 = 56,623,104 int32 (~226.5 MB) -> pure write-BW bound.
// R10 lesson: 55K one-shot blocks ran at ~3.2 TB/s (half of the 6.4 TB/s the
// harness fill kernel hits). Fix: grid-stride per (b,i) row, 1536 blocks,
// 36 stores/thread (G11).

#define B 8
#define N 192
#define C 16
#define ROWS (B * N)          // 1536
#define K4 (N / 4)            // 48 v4i per k-row
#define VPB (N * K4)          // 9216 v4i per (b,i) row
#define ITERS (VPB / 256)     // 36 stores per thread

typedef int   v4i __attribute__((ext_vector_type(4)));
typedef float v4f __attribute__((ext_vector_type(4)));

// Phase 1: argmax of each 16-float row for all three tensors (4608 rows).
// First-occurrence tie-break (strict >).
__global__ void argmax_rows(const float* __restrict__ t0,
                            const float* __restrict__ t1,
                            const float* __restrict__ t2,
                            int* __restrict__ p /* 3*ROWS ints */) {
    int idx = blockIdx.x * blockDim.x + threadIdx.x;
    if (idx >= 3 * ROWS) return;
    int which = idx / ROWS;
    int row   = idx - which * ROWS;
    const float* src = (which == 0) ? t0 : (which == 1) ? t1 : t2;
    const v4f* r = reinterpret_cast<const v4f*>(src + (size_t)row * C);
    float best = -INFINITY;
    int bi = 0;
#pragma unroll
    for (int q = 0; q < 4; ++q) {
        v4f v = r[q];
#pragma unroll
        for (int c = 0; c < 4; ++c) {
            if (v[c] > best) { best = v[c]; bi = q * 4 + c; }
        }
    }
    p[idx] = bi;
}

// Phase 2: one block per (b,i) row. 256 threads x 36 v4i nontemporal stores.
// Per thread, k4 = (t + 256*m) % 48 cycles with period 3 (256 % 48 == 16), so
// only 3 distinct k-vectors -> preloaded into registers.
__global__ __launch_bounds__(256) void joint_candidate(
        const int* __restrict__ p, v4i* __restrict__ out) {
    const int bi = blockIdx.x;           // b*N + i
    const int b  = bi / N;
    const int i  = bi - b * N;
    const int t  = threadIdx.x;
    const int bN = b * N;

    const int* p1 = p + ROWS + bN;       // argmax(t1)[b,:]
    const v4i* p2v = reinterpret_cast<const v4i*>(p + 2 * ROWS + bN);
    const int a0 = p[bi];                // argmax(t0)[b,i] (block-uniform)

    const int r = t % K4;
    int kb[3];
    kb[0] = r; kb[1] = (r + 16) % K4; kb[2] = (r + 32) % K4;
    v4i vk[3];
#pragma unroll
    for (int s = 0; s < 3; ++s) vk[s] = p2v[kb[s]];

    v4i* outrow = out + (size_t)bi * VPB;

#pragma unroll
    for (int m = 0; m < ITERS; ++m) {
        const int pos = t + 256 * m;
        const int j = pos / K4;          // magic-mul
        const int s = m % 3;             // compile-time after unroll
        const v4i v = vk[s];
        const int kbase = kb[s] * 4;
        const int vij = a0 * p1[j];
        const bool inej = (i != j);
        v4i o;
        o.x = (inej && i != kbase     && j != kbase    ) ? vij * v.x : 0;
        o.y = (inej && i != kbase + 1 && j != kbase + 1) ? vij * v.y : 0;
        o.z = (inej && i != kbase + 2 && j != kbase + 2) ? vij * v.z : 0;
        o.w = (inej && i != kbase + 3 && j != kbase + 3) ? vij * v.w : 0;
        // Write-once, never re-read: nontemporal.
        __builtin_nontemporal_store(o, &outrow[pos]);
    }
}

extern "C" void kernel_launch(void* const* d_in, const int* in_sizes, int n_in,
                              void* d_out, int out_size, void* d_ws, size_t ws_size,
                              hipStream_t stream) {
    const float* t0 = (const float*)d_in[0];
    const float* t1 = (const float*)d_in[1];
    const float* t2 = (const float*)d_in[2];
    int* p = (int*)d_ws;                 // 3*1536 ints = 18 KB scratch

    argmax_rows<<<(3 * ROWS + 255) / 256, 256, 0, stream>>>(t0, t1, t2, p);
    joint_candidate<<<ROWS, 256, 0, stream>>>(p, (v4i*)d_out);
}

// Round 12
// 223.305 us; speedup vs baseline: 1.0557x; 1.0557x over previous
//
#include <hip/hip_runtime.h>
#include <math.h>

// Problem: B=8, N=192, C=16.
// out[b,i,j,k] = argmax(t0[b,i,:]) * argmax(t1[b,j,:]) * argmax(t2[b,k,:])
//                * (i!=j && i!=k && j!=k),  written as int32.
// Output: 8*192^3 = 56,623,104 int32 (~226.5 MB) -> pure write-BW bound.
// R11 A/B: identical structure to R11, but PLAIN stores instead of
// __builtin_nontemporal_store. The harness fill kernel sustains 6.3 TB/s
// with cached stores; if nt was the bottleneck (L2-bypass pathology),
// this alone recovers ~6x on the big kernel.

#define B 8
#define N 192
#define C 16
#define ROWS (B * N)          // 1536
#define K4 (N / 4)            // 48 v4i per k-row
#define VPB (N * K4)          // 9216 v4i per (b,i) row
#define ITERS (VPB / 256)     // 36 stores per thread

typedef int   v4i __attribute__((ext_vector_type(4)));
typedef float v4f __attribute__((ext_vector_type(4)));

// Phase 1: argmax of each 16-float row for all three tensors (4608 rows).
// First-occurrence tie-break (strict >).
__global__ void argmax_rows(const float* __restrict__ t0,
                            const float* __restrict__ t1,
                            const float* __restrict__ t2,
                            int* __restrict__ p /* 3*ROWS ints */) {
    int idx = blockIdx.x * blockDim.x + threadIdx.x;
    if (idx >= 3 * ROWS) return;
    int which = idx / ROWS;
    int row   = idx - which * ROWS;
    const float* src = (which == 0) ? t0 : (which == 1) ? t1 : t2;
    const v4f* r = reinterpret_cast<const v4f*>(src + (size_t)row * C);
    float best = -INFINITY;
    int bi = 0;
#pragma unroll
    for (int q = 0; q < 4; ++q) {
        v4f v = r[q];
#pragma unroll
        for (int c = 0; c < 4; ++c) {
            if (v[c] > best) { best = v[c]; bi = q * 4 + c; }
        }
    }
    p[idx] = bi;
}

// Phase 2: one block per (b,i) row. 256 threads x 36 v4i plain stores.
// Per thread, k4 = (t + 256*m) % 48 cycles with period 3 (256 % 48 == 16), so
// only 3 distinct k-vectors -> preloaded into registers.
__global__ __launch_bounds__(256) void joint_candidate(
        const int* __restrict__ p, v4i* __restrict__ out) {
    const int bi = blockIdx.x;           // b*N + i
    const int b  = bi / N;
    const int i  = bi - b * N;
    const int t  = threadIdx.x;
    const int bN = b * N;

    const int* p1 = p + ROWS + bN;       // argmax(t1)[b,:]
    const v4i* p2v = reinterpret_cast<const v4i*>(p + 2 * ROWS + bN);
    const int a0 = p[bi];                // argmax(t0)[b,i] (block-uniform)

    const int r = t % K4;
    int kb[3];
    kb[0] = r; kb[1] = (r + 16) % K4; kb[2] = (r + 32) % K4;
    v4i vk[3];
#pragma unroll
    for (int s = 0; s < 3; ++s) vk[s] = p2v[kb[s]];

    v4i* outrow = out + (size_t)bi * VPB;

#pragma unroll
    for (int m = 0; m < ITERS; ++m) {
        const int pos = t + 256 * m;
        const int j = pos / K4;          // magic-mul
        const int s = m % 3;             // compile-time after unroll
        const v4i v = vk[s];
        const int kbase = kb[s] * 4;
        const int vij = a0 * p1[j];
        const bool inej = (i != j);
        v4i o;
        o.x = (inej && i != kbase     && j != kbase    ) ? vij * v.x : 0;
        o.y = (inej && i != kbase + 1 && j != kbase + 1) ? vij * v.y : 0;
        o.z = (inej && i != kbase + 2 && j != kbase + 2) ? vij * v.z : 0;
        o.w = (inej && i != kbase + 3 && j != kbase + 3) ? vij * v.w : 0;
        outrow[pos] = o;                 // plain cached store (A/B vs R11 nt)
    }
}

extern "C" void kernel_launch(void* const* d_in, const int* in_sizes, int n_in,
                              void* d_out, int out_size, void* d_ws, size_t ws_size,
                              hipStream_t stream) {
    const float* t0 = (const float*)d_in[0];
    const float* t1 = (const float*)d_in[1];
    const float* t2 = (const float*)d_in[2];
    int* p = (int*)d_ws;                 // 3*1536 ints = 18 KB scratch

    argmax_rows<<<(3 * ROWS + 255) / 256, 256, 0, stream>>>(t0, t1, t2, p);
    joint_candidate<<<ROWS, 256, 0, stream>>>(p, (v4i*)d_out);
}